// Round 11
// baseline (144.609 us; speedup 1.0000x reference)
//
#include <hip/hip_runtime.h>
#include <math.h>

#define H    2048
#define H3   6144
#define DIN  1024
#define DOUT 1024
#define NL   4
#define NB   512                  // 2 blocks/CU needed; capacity >= 4 -> 2x margin
#define BT   256                  // 4 waves/block
#define NWAVE (NB * (BT / 64))    // 2048 waves

__device__ __forceinline__ float wave_reduce_sum(float v) {
    #pragma unroll
    for (int off = 32; off; off >>= 1) v += __shfl_down(v, off);
    return v;
}
__device__ __forceinline__ float dot4(float4 w, float4 v, float a) {
    return fmaf(w.x, v.x, fmaf(w.y, v.y, fmaf(w.z, v.z, fmaf(w.w, v.w, a))));
}

// Coherent (Infinity-Cache-level) access for the tiny RW-shared data.
// sc0 sc1 bypasses the non-coherent per-XCD L1/L2 in BOTH directions, fully
// coalesced (R7 post-mortem: scalar __hip_atomic_* loads were the cost; R6
// post-mortem: fence-based flushes were the cost. This path needs neither.)
__device__ __forceinline__ float4 ld_coh4(const float* p) {
    float4 v;
    asm volatile("global_load_dwordx4 %0, %1, off sc0 sc1"
                 : "=v"(v) : "v"(p) : "memory");
    return v;
}
__device__ __forceinline__ float ld_coh1(const float* p) {
    float v;
    asm volatile("global_load_dword %0, %1, off sc0 sc1\n\t"
                 "s_waitcnt vmcnt(0)"
                 : "=v"(v) : "v"(p) : "memory");
    return v;
}
__device__ __forceinline__ void st_coh1(float* p, float v) {
    asm volatile("global_store_dword %0, %1, off sc0 sc1"
                 :: "v"(p), "v"(v) : "memory");
}
// Drain all outstanding vector-memory ops, and fence the scheduler so no
// consumer is hoisted above the wait (guide rule #18).
__device__ __forceinline__ void vm_drain() {
    asm volatile("s_waitcnt vmcnt(0)" ::: "memory");
    __builtin_amdgcn_sched_barrier(0);
}

// Grid barrier: one relaxed agent-scope RMW per block on a monotone counter.
// No cache-maintenance: all cross-block data moves via sc0/sc1 ops.
__device__ __forceinline__ void grid_barrier(int* cnt, int target) {
    asm volatile("s_waitcnt vmcnt(0)" ::: "memory");   // sc1 stores visible
    __syncthreads();
    if (threadIdx.x == 0) {
        __hip_atomic_fetch_add(cnt, 1, __ATOMIC_RELAXED, __HIP_MEMORY_SCOPE_AGENT);
        while (__hip_atomic_load(cnt, __ATOMIC_RELAXED, __HIP_MEMORY_SCOPE_AGENT) < target)
            __builtin_amdgcn_s_sleep(8);
    }
    __syncthreads();
}

__global__ __launch_bounds__(BT, 2) void gru_fused(
    const float* __restrict__ x,    const float* __restrict__ h0,
    const float* __restrict__ encW, const float* __restrict__ encb,
    const float* __restrict__ Wih,  const float* __restrict__ Whh,
    const float* __restrict__ bih,  const float* __restrict__ bhh,
    const float* __restrict__ decW, const float* __restrict__ decb,
    float* __restrict__ out,        float* __restrict__ ws,
    int* __restrict__ cnt)
{
    float* vec0 = ws;           // [H] carry ping   (sc0/sc1 access only)
    float* vec1 = ws + H;       // [H] carry pong   (sc0/sc1 access only)
    float* gh   = ws + 2 * H;   // [NL*3H] hh gates (sc0/sc1 access only)

    const int lane = threadIdx.x & 63;
    const int wid  = threadIdx.x >> 6;
    const int gw   = blockIdx.x * (BT / 64) + wid;   // 0..2047

    // ---------------- Phase 0: encoder (1 row/wave) + gh (12 rows/wave) ----
    {
        const int j = gw;
        const float* rp = encW + (size_t)j * DIN;
        float acc = 0.f;
        #pragma unroll
        for (int p = 0; p < DIN / 256; ++p) {
            int idx = p * 256 + lane * 4;
            acc = dot4(*reinterpret_cast<const float4*>(rp + idx),
                       *reinterpret_cast<const float4*>(x + idx), acc);
        }
        acc = wave_reduce_sum(acc);
        if (lane == 0) st_coh1(vec0 + j, acc + encb[j]);
    }
    for (int g = gw; g < NL * H3; g += NWAVE) {
        const int l = g / H3;
        const float* rp = Whh + (size_t)g * H;
        const float* hv = h0 + l * H;
        float acc = 0.f;
        #pragma unroll
        for (int p = 0; p < H / 256; ++p) {
            int idx = p * 256 + lane * 4;
            float4 h4 = *reinterpret_cast<const float4*>(hv + idx);
            int nz = (h4.x != 0.f) || (h4.y != 0.f) || (h4.z != 0.f) || (h4.w != 0.f);
            if (__any(nz))   // exact-zero chunk skip (bit-identical)
                acc = dot4(*reinterpret_cast<const float4*>(rp + idx), h4, acc);
        }
        acc = wave_reduce_sum(acc);
        if (lane == 0) st_coh1(gh + g, acc + bhh[g]);
    }
    grid_barrier(cnt, NB);

    // ---------------- Phases 1..4: one output element per wave ----------------
    const float* cin = vec0;
    float* cout = vec1;
    for (int l = 0; l < NL; ++l) {
        const int e = gw;
        // Coherent carry preload (8 KB/wave from IC), single drain.
        float4 cv[8];
        #pragma unroll
        for (int p = 0; p < 8; ++p)
            cv[p] = ld_coh4(cin + p * 256 + lane * 4);
        vm_drain();

        const float* hp = h0 + l * H;
        float4 hv[8];
        int nz[8];
        #pragma unroll
        for (int p = 0; p < 8; ++p) {
            hv[p] = *reinterpret_cast<const float4*>(hp + p * 256 + lane * 4);
            nz[p] = __any((hv[p].x != 0.f) || (hv[p].y != 0.f) ||
                          (hv[p].z != 0.f) || (hv[p].w != 0.f));
        }

        const float* Wl = Wih + (size_t)l * H3 * H;
        const float* Hl = Whh + (size_t)l * H3 * H;
        float ai[3], ah[3];
        #pragma unroll
        for (int r = 0; r < 3; ++r) {
            const float* row = Wl + (size_t)(e + r * H) * H;
            float4 wv[8];
            #pragma unroll
            for (int p = 0; p < 8; ++p)
                wv[p] = *reinterpret_cast<const float4*>(row + p * 256 + lane * 4);
            float acc = 0.f;
            #pragma unroll
            for (int p = 0; p < 8; ++p) acc = dot4(wv[p], cv[p], acc);
            ai[r] = acc;
        }
        #pragma unroll
        for (int r = 0; r < 3; ++r) {
            const float* row = Hl + (size_t)(e + r * H) * H;
            float acc = 0.f;
            #pragma unroll
            for (int p = 0; p < 8; ++p)
                if (nz[p])
                    acc = dot4(*reinterpret_cast<const float4*>(row + p * 256 + lane * 4),
                               hv[p], acc);
            ah[r] = acc;
        }

        float s0 = wave_reduce_sum(ai[0]);
        float s1 = wave_reduce_sum(ai[1]);
        float s2 = wave_reduce_sum(ai[2]);
        float t0 = wave_reduce_sum(ah[0]);
        float t1 = wave_reduce_sum(ah[1]);
        float t2 = wave_reduce_sum(ah[2]);
        if (lane == 0) {
            const float* gl = gh + (size_t)l * H3;
            const float* bl = bih + (size_t)l * H3;
            const float* cl = bhh + (size_t)l * H3;
            float r = 1.f / (1.f + expf(-(s0 + bl[e] + t0 + cl[e])));
            float z = 1.f / (1.f + expf(-(s1 + bl[H + e] + t1 + cl[H + e])));
            // note: gh holds precomputed hh gates ONLY for phase-0 use pattern;
            // here t* already includes this layer's hh dot, cl[] its bias.
            (void)gl;
            float n = tanhf(s2 + bl[2 * H + e] + r * (t2 + cl[2 * H + e]));
            float h = hp[e];
            float hnew = (1.f - z) * n + z * h;
            st_coh1(cout + e, hnew);
            out[DOUT + l * H + e] = hnew;
        }
        grid_barrier(cnt, (2 + l) * NB);
        const float* t = cin; cin = cout; cout = (float*)t;
    }

    // ---------------- Phase 5: decoder (wave per row, waves 0..1023) ---------
    if (gw < DOUT) {
        const int row = gw;
        float4 cv[8];
        #pragma unroll
        for (int p = 0; p < 8; ++p)
            cv[p] = ld_coh4(cin + p * 256 + lane * 4);
        vm_drain();
        const float* rp = decW + (size_t)row * H;
        float acc = 0.f;
        #pragma unroll
        for (int p = 0; p < 8; ++p)
            acc = dot4(*reinterpret_cast<const float4*>(rp + p * 256 + lane * 4),
                       cv[p], acc);
        acc = wave_reduce_sum(acc);
        if (lane == 0) out[row] = acc + decb[row];
    }
}

extern "C" void kernel_launch(void* const* d_in, const int* in_sizes, int n_in,
                              void* d_out, int out_size, void* d_ws, size_t ws_size,
                              hipStream_t stream) {
    const float* x    = (const float*)d_in[0];
    const float* h0   = (const float*)d_in[1];
    const float* encW = (const float*)d_in[2];
    const float* encb = (const float*)d_in[3];
    const float* Wih  = (const float*)d_in[4];
    const float* Whh  = (const float*)d_in[5];
    const float* bih  = (const float*)d_in[6];
    const float* bhh  = (const float*)d_in[7];
    const float* decW = (const float*)d_in[8];
    const float* decb = (const float*)d_in[9];
    float* out = (float*)d_out;
    float* ws  = (float*)d_ws;

    int* cnt = (int*)((char*)d_ws + (1 << 20));
    (void)hipMemsetAsync((void*)cnt, 0, 64, stream);

    gru_fused<<<NB, BT, 0, stream>>>(x, h0, encW, encb, Wih, Whh, bih, bhh,
                                     decW, decb, out, ws, cnt);
}

// Round 12
// 54.364 us; speedup vs baseline: 2.6600x; 2.6600x over previous
//
#include <hip/hip_runtime.h>
#include <math.h>

#define H 2048
#define DIN 1024
#define DOUT 1024
#define NL 4

__device__ __forceinline__ float wave_reduce_sum(float v) {
    #pragma unroll
    for (int off = 32; off; off >>= 1) v += __shfl_down(v, off);
    return v;
}
__device__ __forceinline__ float dot4(float4 w, float4 v, float a) {
    return fmaf(w.x, v.x, fmaf(w.y, v.y, fmaf(w.z, v.z, fmaf(w.w, v.w, a))));
}
// XCD-aware bijective block swizzle (T1): MI355X has 8 XCDs; default dispatch
// round-robins blocks across them. This remap gives each XCD a CONTIGUOUS
// band of blocks -> contiguous weight-row ranges per XCD (DRAM/IC locality).
// Valid (bijective) because all grids here have nb % 8 == 0.
__device__ __forceinline__ int xcd_swz(int b, int nb) {
    return (b & 7) * (nb >> 3) + (b >> 3);
}

// Generic GEMV: y[r] = dot(W[r,:], x) + b[r]. One 64-lane wave per row.
template <int K>
__global__ __launch_bounds__(256) void gemv_kernel(
    const float* __restrict__ W, const float* __restrict__ x,
    const float* __restrict__ b, float* __restrict__ y, int N) {
    int blk  = xcd_swz(blockIdx.x, gridDim.x);
    int wave = (blk * blockDim.x + threadIdx.x) >> 6;
    int lane = threadIdx.x & 63;
    if (wave >= N) return;
    const float* row = W + (size_t)wave * K;
    float acc = 0.f;
    #pragma unroll
    for (int i = 0; i < K / 256; ++i) {
        int idx = i * 256 + lane * 4;
        acc = dot4(*reinterpret_cast<const float4*>(row + idx),
                   *reinterpret_cast<const float4*>(x + idx), acc);
    }
    acc = wave_reduce_sum(acc);
    if (lane == 0) y[wave] = acc + b[wave];
}

// Fused per-layer GRU step (R8 body, best anchor 53.1us): one wave per output
// element, 6 interleaved dots + exact-zero chunk skip on the W_hh stream
// (bit-identical: fmaf(w,0,acc)==acc for finite w). R12 change: XCD swizzle
// on the block index only.
__global__ __launch_bounds__(256) void gru_layer_kernel(
    const float* __restrict__ Wi,    // [3H, H] this layer
    const float* __restrict__ Wh,    // [3H, H] this layer
    const float* __restrict__ bi,    // [3H]
    const float* __restrict__ bh,    // [3H]
    const float* __restrict__ hprev, // [H] = h0[l]
    const float* __restrict__ cin,   // [H]
    float* __restrict__ cout,        // [H]
    float* __restrict__ hid_out) {   // [H] slice of d_out
    int blk  = xcd_swz(blockIdx.x, gridDim.x);
    int wave = (blk * blockDim.x + threadIdx.x) >> 6;
    int lane = threadIdx.x & 63;
    if (wave >= H) return;
    const float* ir_row = Wi + (size_t)wave * H;
    const float* iz_row = Wi + (size_t)(wave + H) * H;
    const float* in_row = Wi + (size_t)(wave + 2 * H) * H;
    const float* hr_row = Wh + (size_t)wave * H;
    const float* hz_row = Wh + (size_t)(wave + H) * H;
    const float* hn_row = Wh + (size_t)(wave + 2 * H) * H;
    float air = 0.f, aiz = 0.f, ain = 0.f;
    float ahr = 0.f, ahz = 0.f, ahn = 0.f;
    #pragma unroll
    for (int i = 0; i < H / 256; ++i) {
        int idx = i * 256 + lane * 4;
        float4 xv = *reinterpret_cast<const float4*>(cin + idx);
        float4 hv = *reinterpret_cast<const float4*>(hprev + idx);
        air = dot4(*reinterpret_cast<const float4*>(ir_row + idx), xv, air);
        aiz = dot4(*reinterpret_cast<const float4*>(iz_row + idx), xv, aiz);
        ain = dot4(*reinterpret_cast<const float4*>(in_row + idx), xv, ain);
        int nz = (hv.x != 0.f) || (hv.y != 0.f) || (hv.z != 0.f) || (hv.w != 0.f);
        if (__any(nz)) {
            ahr = dot4(*reinterpret_cast<const float4*>(hr_row + idx), hv, ahr);
            ahz = dot4(*reinterpret_cast<const float4*>(hz_row + idx), hv, ahz);
            ahn = dot4(*reinterpret_cast<const float4*>(hn_row + idx), hv, ahn);
        }
    }
    air = wave_reduce_sum(air);
    aiz = wave_reduce_sum(aiz);
    ain = wave_reduce_sum(ain);
    ahr = wave_reduce_sum(ahr);
    ahz = wave_reduce_sum(ahz);
    ahn = wave_reduce_sum(ahn);
    if (lane == 0) {
        float ir  = air + bi[wave];
        float iz  = aiz + bi[H + wave];
        float inn = ain + bi[2 * H + wave];
        float hr  = ahr + bh[wave];
        float hz  = ahz + bh[H + wave];
        float hn  = ahn + bh[2 * H + wave];
        float r = 1.f / (1.f + expf(-(ir + hr)));
        float z = 1.f / (1.f + expf(-(iz + hz)));
        float n = tanhf(inn + r * hn);
        float h = hprev[wave];
        float hnew = (1.f - z) * n + z * h;
        cout[wave] = hnew;
        hid_out[wave] = hnew;
    }
}

extern "C" void kernel_launch(void* const* d_in, const int* in_sizes, int n_in,
                              void* d_out, int out_size, void* d_ws, size_t ws_size,
                              hipStream_t stream) {
    const float* x    = (const float*)d_in[0];
    const float* h0   = (const float*)d_in[1];
    const float* encW = (const float*)d_in[2];
    const float* encb = (const float*)d_in[3];
    const float* Wih  = (const float*)d_in[4];
    const float* Whh  = (const float*)d_in[5];
    const float* bih  = (const float*)d_in[6];
    const float* bhh  = (const float*)d_in[7];
    const float* decW = (const float*)d_in[8];
    const float* decb = (const float*)d_in[9];
    float* out = (float*)d_out;

    float* vec0 = (float*)d_ws;      // [H]
    float* vec1 = vec0 + H;          // [H]

    // 1) encoder: [1,1024] -> [1,2048]
    gemv_kernel<DIN><<<H / 4, 256, 0, stream>>>(encW, x, encb, vec0, H);
    // 2) sequential fused GRU layers, ping-pong carry
    const float* cin = vec0;
    float* cout = vec1;
    for (int l = 0; l < NL; ++l) {
        gru_layer_kernel<<<H / 4, 256, 0, stream>>>(
            Wih + (size_t)l * 3 * H * H, Whh + (size_t)l * 3 * H * H,
            bih + l * 3 * H, bhh + l * 3 * H,
            h0 + l * H, cin, cout, out + DOUT + l * H);
        float* t = cout; cout = (float*)cin; cin = t;
    }
    // 3) decoder: [1,2048] -> [1,1024]
    gemv_kernel<H><<<DOUT / 4, 256, 0, stream>>>(decW, cin, decb, out, DOUT);
}

// Round 14
// 52.682 us; speedup vs baseline: 2.7449x; 1.0319x over previous
//
#include <hip/hip_runtime.h>
#include <math.h>

#define H 2048
#define DIN 1024
#define DOUT 1024
#define NL 4

// FINAL (R8 structure, best measured 53.1 us; R13 bench was an infra failure
// — resubmitting unchanged).
// Structure: 6 dispatches (enc GEMV, 4 fused GRU-layer kernels, dec GEMV).
// Key win: exact-zero chunk skip on the W_hh streams (bit-identical since
// fmaf(w,0,acc)==acc for finite w) -> 419 MB -> 218 MB traffic, L3-resident.
// Measured-null levers: occupancy (R3), deep ILP (R9/R10), XCD swizzle (R12).
// Measured-worse: persistent kernel w/ grid barrier (R6/R7/R11: barrier
// >= 30us vs ~2.5us dispatch boundary on MI355X).

__device__ __forceinline__ float wave_reduce_sum(float v) {
    #pragma unroll
    for (int off = 32; off; off >>= 1) v += __shfl_down(v, off);
    return v;
}
__device__ __forceinline__ float dot4(float4 w, float4 v, float a) {
    return fmaf(w.x, v.x, fmaf(w.y, v.y, fmaf(w.z, v.z, fmaf(w.w, v.w, a))));
}

// Generic GEMV: y[r] = dot(W[r,:], x) + b[r]. One 64-lane wave per row.
template <int K>
__global__ __launch_bounds__(256) void gemv_kernel(
    const float* __restrict__ W, const float* __restrict__ x,
    const float* __restrict__ b, float* __restrict__ y, int N) {
    int wave = (blockIdx.x * blockDim.x + threadIdx.x) >> 6;
    int lane = threadIdx.x & 63;
    if (wave >= N) return;
    const float* row = W + (size_t)wave * K;
    float acc = 0.f;
    #pragma unroll
    for (int i = 0; i < K / 256; ++i) {
        int idx = i * 256 + lane * 4;
        acc = dot4(*reinterpret_cast<const float4*>(row + idx),
                   *reinterpret_cast<const float4*>(x + idx), acc);
    }
    acc = wave_reduce_sum(acc);
    if (lane == 0) y[wave] = acc + b[wave];
}

// Fused per-layer GRU step: one wave per output element, 6 dots
// ({r,z,n} x {W_ih over carry, W_hh over h0[l]}) + gate math, with the
// exact-zero chunk skip on the W_hh stream.
__global__ __launch_bounds__(256) void gru_layer_kernel(
    const float* __restrict__ Wi,    // [3H, H] this layer
    const float* __restrict__ Wh,    // [3H, H] this layer
    const float* __restrict__ bi,    // [3H]
    const float* __restrict__ bh,    // [3H]
    const float* __restrict__ hprev, // [H] = h0[l]
    const float* __restrict__ cin,   // [H]
    float* __restrict__ cout,        // [H]
    float* __restrict__ hid_out) {   // [H] slice of d_out
    int wave = (blockIdx.x * blockDim.x + threadIdx.x) >> 6;
    int lane = threadIdx.x & 63;
    if (wave >= H) return;
    const float* ir_row = Wi + (size_t)wave * H;
    const float* iz_row = Wi + (size_t)(wave + H) * H;
    const float* in_row = Wi + (size_t)(wave + 2 * H) * H;
    const float* hr_row = Wh + (size_t)wave * H;
    const float* hz_row = Wh + (size_t)(wave + H) * H;
    const float* hn_row = Wh + (size_t)(wave + 2 * H) * H;
    float air = 0.f, aiz = 0.f, ain = 0.f;
    float ahr = 0.f, ahz = 0.f, ahn = 0.f;
    #pragma unroll
    for (int i = 0; i < H / 256; ++i) {
        int idx = i * 256 + lane * 4;
        float4 xv = *reinterpret_cast<const float4*>(cin + idx);
        float4 hv = *reinterpret_cast<const float4*>(hprev + idx);
        air = dot4(*reinterpret_cast<const float4*>(ir_row + idx), xv, air);
        aiz = dot4(*reinterpret_cast<const float4*>(iz_row + idx), xv, aiz);
        ain = dot4(*reinterpret_cast<const float4*>(in_row + idx), xv, ain);
        int nz = (hv.x != 0.f) || (hv.y != 0.f) || (hv.z != 0.f) || (hv.w != 0.f);
        if (__any(nz)) {
            ahr = dot4(*reinterpret_cast<const float4*>(hr_row + idx), hv, ahr);
            ahz = dot4(*reinterpret_cast<const float4*>(hz_row + idx), hv, ahz);
            ahn = dot4(*reinterpret_cast<const float4*>(hn_row + idx), hv, ahn);
        }
    }
    air = wave_reduce_sum(air);
    aiz = wave_reduce_sum(aiz);
    ain = wave_reduce_sum(ain);
    ahr = wave_reduce_sum(ahr);
    ahz = wave_reduce_sum(ahz);
    ahn = wave_reduce_sum(ahn);
    if (lane == 0) {
        float ir  = air + bi[wave];
        float iz  = aiz + bi[H + wave];
        float inn = ain + bi[2 * H + wave];
        float hr  = ahr + bh[wave];
        float hz  = ahz + bh[H + wave];
        float hn  = ahn + bh[2 * H + wave];
        float r = 1.f / (1.f + expf(-(ir + hr)));
        float z = 1.f / (1.f + expf(-(iz + hz)));
        float n = tanhf(inn + r * hn);
        float h = hprev[wave];
        float hnew = (1.f - z) * n + z * h;
        cout[wave] = hnew;
        hid_out[wave] = hnew;
    }
}

extern "C" void kernel_launch(void* const* d_in, const int* in_sizes, int n_in,
                              void* d_out, int out_size, void* d_ws, size_t ws_size,
                              hipStream_t stream) {
    const float* x    = (const float*)d_in[0];
    const float* h0   = (const float*)d_in[1];
    const float* encW = (const float*)d_in[2];
    const float* encb = (const float*)d_in[3];
    const float* Wih  = (const float*)d_in[4];
    const float* Whh  = (const float*)d_in[5];
    const float* bih  = (const float*)d_in[6];
    const float* bhh  = (const float*)d_in[7];
    const float* decW = (const float*)d_in[8];
    const float* decb = (const float*)d_in[9];
    float* out = (float*)d_out;

    float* vec0 = (float*)d_ws;      // [H]
    float* vec1 = vec0 + H;          // [H]

    // 1) encoder: [1,1024] -> [1,2048]
    gemv_kernel<DIN><<<H / 4, 256, 0, stream>>>(encW, x, encb, vec0, H);
    // 2) sequential fused GRU layers, ping-pong carry
    const float* cin = vec0;
    float* cout = vec1;
    for (int l = 0; l < NL; ++l) {
        gru_layer_kernel<<<H / 4, 256, 0, stream>>>(
            Wih + (size_t)l * 3 * H * H, Whh + (size_t)l * 3 * H * H,
            bih + l * 3 * H, bhh + l * 3 * H,
            h0 + l * H, cin, cout, out + DOUT + l * H);
        float* t = cout; cout = (float*)cin; cin = t;
    }
    // 3) decoder: [1,2048] -> [1,1024]
    gemv_kernel<H><<<DOUT / 4, 256, 0, stream>>>(decW, cin, decb, out, DOUT);
}